// Round 19
// baseline (43.241 us; speedup 1.0000x reference)
//
#include <hip/hip_runtime.h>

#define FH 128
#define FW 128
#define CPLANE 490                 // 10*7*7 input channels; plane c_in serves bin (ph,pw)
#define NBATCH 4
#define NPLANES (NBATCH * CPLANE)  // 1960 = 8 * 245
#define CHUNK (NPLANES / 8)        // 245 planes per XCD chunk; 490=2*245 -> one batch/chunk
#define SSCALE 0.0625f
#define PLFL (FH * FW)             // 16384 floats
#define GRIDB 512                  // persistent: 2 blocks/CU
#define BPX (GRIDB / 8)            // 64 blocks per XCD chunk
// dynamic LDS: plane (16384 f) + u16 list (1024 f) + misc ints (32 f)
#define LDS_FLOATS (PLFL + 1024 + 32)

typedef float f32x4 __attribute__((ext_vector_type(4)));
typedef unsigned long long u64;
typedef unsigned short u16;

// Persistent fused kernel. Per block: scan its batch ONCE (overlapped under
// the first plane's staging loads), then loop planes popped from a per-XCD
// counter (ws[xcd]) -- dynamic balance, no dispatch tail, XCD write-merge
// preserved (blocks only take planes from their own chunk).
__global__ __launch_bounds__(1024, 8) void psroi_persist(const float* __restrict__ feat,
                                                         const float* __restrict__ rois,
                                                         int* __restrict__ ws,
                                                         float* __restrict__ out, int R) {
    extern __shared__ float dbuf[];
    float* const plane  = dbuf;
    u16*   const list16 = (u16*)(dbuf + PLFL);
    int*   const misc   = (int*)(dbuf + PLFL + 1024);   // [0]=next seq, [1..16]=wtot

    const int tid = threadIdx.x;
    const int bid = blockIdx.x;
    const int xcd = bid & 7;
    const int b   = xcd >> 1;                 // chunk -> batch (490 = 2*245)

    // ---- first plane (static): issue staging loads immediately ----
    int seq = bid >> 3;                       // 0..63 < 245
    const f32x4* src = (const f32x4*)(feat + (size_t)(xcd * CHUNK + seq) * PLFL);
    f32x4 s0 = src[0 * 1024 + tid];
    f32x4 s1 = src[1 * 1024 + tid];
    f32x4 s2 = src[2 * 1024 + tid];
    f32x4 s3 = src[3 * 1024 + tid];

    // ---- scan this batch ONCE (overlaps the loads above) ----
    const int i0 = tid * 2, i1 = i0 + 1;
    const bool m0 = (i0 < R) && ((int)rois[(size_t)i0 * 5] == b);
    const bool m1 = (i1 < R) && ((int)rois[(size_t)i1 * 5] == b);
    const u64 bl0 = __ballot(m0);
    const u64 bl1 = __ballot(m1);
    const int w    = tid >> 6;
    const int lane = tid & 63;
    const u64 below = ((u64)1 << lane) - 1;
    if (lane == 0) misc[1 + w] = __popcll(bl0) + __popcll(bl1);
    __syncthreads();

    int nb = 0, woff = 0;
#pragma unroll
    for (int ww = 0; ww < 16; ++ww) {
        const int c = misc[1 + ww];
        if (ww < w) woff += c;
        nb += c;
    }
    const int p0 = woff + __popcll(bl0 & below) + __popcll(bl1 & below);
    if (m0) list16[p0] = (u16)i0;
    if (m1) list16[p0 + (m0 ? 1 : 0)] = (u16)i1;
    __syncthreads();                          // list ready (persists all iterations)

    // ---- commit first plane ----
    *(f32x4*)(plane + (0 * 1024 + tid) * 4) = s0;
    *(f32x4*)(plane + (1 * 1024 + tid) * 4) = s1;
    *(f32x4*)(plane + (2 * 1024 + tid) * 4) = s2;
    *(f32x4*)(plane + (3 * 1024 + tid) * 4) = s3;
    __syncthreads();

    const int   sub = tid & 3;                // bilinear sample id
    const float sy  = 0.25f + 0.5f * (float)(sub >> 1);
    const float sx  = 0.25f + 0.5f * (float)(sub & 1);
    const int   kb  = tid >> 2;

    for (;;) {
        // ---- gather current plane ----
        const int pl   = xcd * CHUNK + seq;
        const int c_in = pl - b * CPLANE;
        const int pw   = c_in % 7;
        const int ph   = (c_in / 7) % 7;

        for (int base = 0; base < nb; base += 256) {
            const int k = base + kb;
            if (k < nb) {
                const int ri = list16[k];
                const float* roi = rois + (size_t)ri * 5;   // hot 40 KB, cache-resident
                const float x1 = roi[1] * SSCALE;
                const float y1 = roi[2] * SSCALE;
                const float bw = fmaxf(roi[3] * SSCALE - x1, 0.1f) * (1.0f / 7.0f);
                const float bh = fmaxf(roi[4] * SSCALE - y1, 0.1f) * (1.0f / 7.0f);

                float y = y1 + ((float)ph + sy) * bh;
                y = fminf(fmaxf(y, 0.0f), 127.0f);
                float y0f = floorf(y);
                int   y0  = (int)y0f;
                float ly  = y - y0f;
                if (y0 > 126) { y0 = 126; ly = 1.0f; }   // y==127 -> full weight row 127

                float x = x1 + ((float)pw + sx) * bw;
                x = fminf(fmaxf(x, 0.0f), 127.0f);
                float x0f = floorf(x);
                int   x0  = (int)x0f;
                float lx  = x - x0f;
                if (x0 > 126) { x0 = 126; lx = 1.0f; }

                const float* p = plane + y0 * FW + x0;
                const float v00 = p[0];
                const float v01 = p[1];
                const float v10 = p[FW];
                const float v11 = p[FW + 1];

                const float top = v00 + (v01 - v00) * lx;
                const float bot = v10 + (v11 - v10) * lx;
                float val = top + (bot - top) * ly;

                val += __shfl_xor(val, 1);
                val += __shfl_xor(val, 2);
                if (sub == 0) out[(size_t)ri * CPLANE + c_in] = val * 0.25f;
            }
        }

        // ---- pop next plane (overlaps tail of gather for other waves) ----
        if (tid == 0) misc[0] = BPX + atomicAdd(&ws[xcd], 1);
        __syncthreads();                       // gather done + next seq visible
        const int ns = misc[0];
        if (ns >= CHUNK) break;
        seq = ns;

        // ---- stage next plane ----
        const f32x4* srcn = (const f32x4*)(feat + (size_t)(xcd * CHUNK + seq) * PLFL);
        f32x4 t0 = srcn[0 * 1024 + tid];
        f32x4 t1 = srcn[1 * 1024 + tid];
        f32x4 t2 = srcn[2 * 1024 + tid];
        f32x4 t3 = srcn[3 * 1024 + tid];
        *(f32x4*)(plane + (0 * 1024 + tid) * 4) = t0;
        *(f32x4*)(plane + (1 * 1024 + tid) * 4) = t1;
        *(f32x4*)(plane + (2 * 1024 + tid) * 4) = t2;
        *(f32x4*)(plane + (3 * 1024 + tid) * 4) = t3;
        __syncthreads();
    }
}

extern "C" void kernel_launch(void* const* d_in, const int* in_sizes, int n_in,
                              void* d_out, int out_size, void* d_ws, size_t ws_size,
                              hipStream_t stream) {
    const float* feat = (const float*)d_in[0];
    const float* rois = (const float*)d_in[1];
    float* out = (float*)d_out;
    int* ws = (int*)d_ws;

    const int R = in_sizes[1] / 5;   // 2048 (kernel assumes R <= 2048)

    static bool attr_set = false;    // host-side, idempotent (R16-proven pattern)
    if (!attr_set) {
        hipFuncSetAttribute((const void*)psroi_persist,
                            hipFuncAttributeMaxDynamicSharedMemorySize, LDS_FLOATS * 4);
        attr_set = true;
    }

    hipMemsetAsync(d_ws, 0, 8 * sizeof(int), stream);   // per-XCD plane counters
    psroi_persist<<<GRIDB, 1024, LDS_FLOATS * 4, stream>>>(feat, rois, ws, out, R);
}

// Round 20
// 32.641 us; speedup vs baseline: 1.3248x; 1.3248x over previous
//
#include <hip/hip_runtime.h>

#define FH 128
#define FW 128
#define CPLANE 490                 // 10*7*7 input channels; plane c_in serves bin (ph,pw)
#define NBATCH 4
#define NPLANES (NBATCH * CPLANE)  // 1960 = 8 * 245
#define SSCALE 0.0625f

typedef float f32x4 __attribute__((ext_vector_type(4)));

// Single fused kernel: one plane per block (XCD-chunked), self-built roi list.
// R18 proven-best: plain staging loads, ballot compaction under load latency,
// short-lived blocks (phase diversity via dispatch, beats hand pipelines).
__global__ __launch_bounds__(1024, 8) void psroi_fused(const float* __restrict__ feat,
                                                       const float* __restrict__ rois,
                                                       float* __restrict__ out, int R) {
    __shared__ float plane[FH * FW];           // exactly 64 KB -> 2 blocks/CU
    int* const lint = (int*)plane;             // compacted roi list (ints 0..2047)
    int* const wtot = (int*)plane + (FH * FW - 16);  // 16 per-wave counts (tail region)

    const int tid = threadIdx.x;
    const int bid = blockIdx.x;
    const int pl  = (bid & 7) * (NPLANES / 8) + (bid >> 3);  // bijective XCD chunking
    const int b    = pl / CPLANE;
    const int c_in = pl - b * CPLANE;
    const int pw   = c_in % 7;
    const int ph   = (c_in / 7) % 7;

    // ---- phase 0: issue full-plane PLAIN loads; in flight through the scan ----
    const f32x4* __restrict__ src = (const f32x4*)(feat + (size_t)pl * (FH * FW));
    f32x4 s0 = src[0 * 1024 + tid];
    f32x4 s1 = src[1 * 1024 + tid];
    f32x4 s2 = src[2 * 1024 + tid];
    f32x4 s3 = src[3 * 1024 + tid];

    // ---- phase 1: scan rois (2/thread), deterministic ballot compaction ----
    const int i0 = tid * 2, i1 = i0 + 1;
    bool m0 = false, m1 = false;
    if (i0 < R) m0 = ((int)rois[(size_t)i0 * 5] == b);
    if (i1 < R) m1 = ((int)rois[(size_t)i1 * 5] == b);
    const unsigned long long bl0 = __ballot(m0);
    const unsigned long long bl1 = __ballot(m1);
    const int w    = tid >> 6;
    const int lane = tid & 63;
    const unsigned long long below = ((unsigned long long)1 << lane) - 1;
    if (lane == 0) wtot[w] = __popcll(bl0) + __popcll(bl1);
    __syncthreads();

    int nb = 0, woff = 0;
#pragma unroll
    for (int ww = 0; ww < 16; ++ww) {
        const int c = wtot[ww];
        if (ww < w) woff += c;
        nb += c;
    }
    const int p0 = woff + __popcll(bl0 & below) + __popcll(bl1 & below);
    if (m0) lint[p0] = i0;
    if (m1) lint[p0 + (m0 ? 1 : 0)] = i1;
    __syncthreads();

    // ---- phase 2: lift my <=8 gather entries into named regs (rule #20) ----
    const int kb = tid >> 2;
    const int r0 = lint[kb];
    const int r1 = lint[kb + 256];
    const int r2 = lint[kb + 512];
    const int r3 = lint[kb + 768];
    const int r4 = lint[kb + 1024];
    const int r5 = lint[kb + 1280];
    const int r6 = lint[kb + 1536];
    const int r7 = lint[kb + 1792];
    __syncthreads();                 // list fully consumed; plane may overwrite

    // ---- phase 3: commit staged plane to LDS (vmcnt wait lands here) ----
    *(f32x4*)(plane + (0 * 1024 + tid) * 4) = s0;
    *(f32x4*)(plane + (1 * 1024 + tid) * 4) = s1;
    *(f32x4*)(plane + (2 * 1024 + tid) * 4) = s2;
    *(f32x4*)(plane + (3 * 1024 + tid) * 4) = s3;
    __syncthreads();

    // ---- phase 4: gather, 4 lanes per roi ----
    const int   sub = tid & 3;
    const float sy  = 0.25f + 0.5f * (float)(sub >> 1);
    const float sx  = 0.25f + 0.5f * (float)(sub & 1);

    auto gather = [&](int k, int ri) {
        if (k < nb) {
            const float* roi = rois + (size_t)ri * 5;   // hot 40 KB, cache-resident
            const float x1 = roi[1] * SSCALE;
            const float y1 = roi[2] * SSCALE;
            const float bw = fmaxf(roi[3] * SSCALE - x1, 0.1f) * (1.0f / 7.0f);
            const float bh = fmaxf(roi[4] * SSCALE - y1, 0.1f) * (1.0f / 7.0f);

            float y = y1 + ((float)ph + sy) * bh;
            y = fminf(fmaxf(y, 0.0f), 127.0f);
            float y0f = floorf(y);
            int   y0  = (int)y0f;
            float ly  = y - y0f;
            if (y0 > 126) { y0 = 126; ly = 1.0f; }   // y==127 -> full weight on row 127

            float x = x1 + ((float)pw + sx) * bw;
            x = fminf(fmaxf(x, 0.0f), 127.0f);
            float x0f = floorf(x);
            int   x0  = (int)x0f;
            float lx  = x - x0f;
            if (x0 > 126) { x0 = 126; lx = 1.0f; }

            const float* p = plane + y0 * FW + x0;
            const float v00 = p[0];
            const float v01 = p[1];
            const float v10 = p[FW];
            const float v11 = p[FW + 1];

            const float top = v00 + (v01 - v00) * lx;
            const float bot = v10 + (v11 - v10) * lx;
            float val = top + (bot - top) * ly;

            val += __shfl_xor(val, 1);
            val += __shfl_xor(val, 2);
            if (sub == 0) out[(size_t)ri * CPLANE + c_in] = val * 0.25f;
        }
    };
    gather(kb,        r0);
    gather(kb + 256,  r1);
    gather(kb + 512,  r2);
    gather(kb + 768,  r3);
    gather(kb + 1024, r4);
    gather(kb + 1280, r5);
    gather(kb + 1536, r6);
    gather(kb + 1792, r7);
}

extern "C" void kernel_launch(void* const* d_in, const int* in_sizes, int n_in,
                              void* d_out, int out_size, void* d_ws, size_t ws_size,
                              hipStream_t stream) {
    const float* feat = (const float*)d_in[0];
    const float* rois = (const float*)d_in[1];
    float* out = (float*)d_out;

    const int R = in_sizes[1] / 5;   // 2048 (kernel assumes R <= 2048)

    psroi_fused<<<NPLANES, 1024, 0, stream>>>(feat, rois, out, R);
}